// Round 1
// 1512.851 us; speedup vs baseline: 1.0372x; 1.0372x over previous
//
#include <hip/hip_runtime.h>
#include <cstdint>
#include <cstddef>

// DotAttention: B=32, T_dec=T_enc=2048, D=512, Dv=512
//   scores = softmax(QK^T/sqrt(D) - (i - j)/32, axis=j)   [fp32, output 1]
//   summaries = scores @ V                                 [fp32, output 0]
//
// R1: softmax fused away. gemm1 epilogue emits per-row partial (max, sumexp)
// for its 128-col slice (stored in the summaries buffer O, cols 0..63, which
// gemm2 consumes for its own rows before overwriting them). gemm2 merges the
// 32 partials per row in its prologue and applies P = exp(l-M)*invS during
// A-staging, writing normalized fp32 P back to Sc (scores output) in the same
// pass. Sc traffic 2148 -> 1611 MB; standalone softmax kernel removed.

#define NB 32
#define TD 2048
#define TE 2048
#define DQ 512
#define DV 512

static constexpr float SCALE = 0.04419417382415922f;  // 1/sqrt(512)
static constexpr float WBIAS = 0.03125f;              // 1/(2*sigma^2), sigma=4

typedef __bf16 bf16x8 __attribute__((ext_vector_type(8)));
typedef float f32x4 __attribute__((ext_vector_type(4)));

__device__ __forceinline__ unsigned short f2bf(float x) {
  unsigned int u = __float_as_uint(x);
  u = (u + 0x7fffu + ((u >> 16) & 1u)) >> 16;  // RNE
  return (unsigned short)u;
}

// async global->LDS, 16B per lane; LDS dest is wave-uniform base + lane*16
__device__ __forceinline__ void gload_lds16(const void* g, void* l) {
  __builtin_amdgcn_global_load_lds(
      (const __attribute__((address_space(1))) void*)g,
      (__attribute__((address_space(3))) void*)l, 16, 0, 0);
}

// ---------------- cast fp32 -> bf16 (Q and K in one launch) ----------------
__global__ __launch_bounds__(256) void k_cvt2(const float4* __restrict__ Q,
                                              ushort4* __restrict__ Qb,
                                              const float4* __restrict__ K,
                                              ushort4* __restrict__ Kb) {
  int bid = blockIdx.x;
  const float4* s;
  ushort4* d;
  int i;
  if (bid < 32768) {
    s = Q; d = Qb; i = bid * 256 + threadIdx.x;
  } else {
    s = K; d = Kb; i = (bid - 32768) * 256 + threadIdx.x;
  }
  float4 v = s[i];
  d[i] = make_ushort4(f2bf(v.x), f2bf(v.y), f2bf(v.z), f2bf(v.w));
}

// ---------------- transpose-cast V [b][j][v] fp32 -> Vt [b][v][j] bf16 ----------------
__global__ __launch_bounds__(256) void k_vtrans(const float* __restrict__ V,
                                                unsigned short* __restrict__ Vt) {
  __shared__ float t[32 * 33];
  int b = blockIdx.z, j0 = blockIdx.y * 32, v0 = blockIdx.x * 32;
  int tid = threadIdx.x;
  int r = tid >> 3, c4 = (tid & 7) * 4;
  float4 in = *(const float4*)(V + ((size_t)b * TE + j0 + r) * DV + v0 + c4);
  t[r * 33 + c4 + 0] = in.x;
  t[r * 33 + c4 + 1] = in.y;
  t[r * 33 + c4 + 2] = in.z;
  t[r * 33 + c4 + 3] = in.w;
  __syncthreads();
  ushort4 o = make_ushort4(f2bf(t[(c4 + 0) * 33 + r]), f2bf(t[(c4 + 1) * 33 + r]),
                           f2bf(t[(c4 + 2) * 33 + r]), f2bf(t[(c4 + 3) * 33 + r]));
  *(ushort4*)(Vt + ((size_t)b * DV + v0 + r) * TE + j0 + c4) = o;
}

// ---------------- GEMM1: logits = Qb Kb^T * SCALE - (i-j)*WBIAS ----------------
// 128x128 tile, BK=32, 4 waves, 4x4 16x16x32 MFMA tiles per wave (m97 structure)
// Epilogue additionally reduces per-row partial (max, sum-exp) over this
// block's 128-col slice and stores them into St (=O) at cols [p] and [32+p],
// p = jt*2 + (w&1)  (32 partials per row across the 16 jt blocks x 2 wave-cols).
__global__ __launch_bounds__(256) void k_gemm1(const unsigned short* __restrict__ Qb,
                                               const unsigned short* __restrict__ Kb,
                                               float* __restrict__ Sc,
                                               float* __restrict__ St) {
  __shared__ __align__(16) unsigned short As[128 * 32];
  __shared__ __align__(16) unsigned short Bs[128 * 32];
  int bid = blockIdx.x;
  // XCD swizzle: keep each batch's 256 blocks on one XCD (L2 locality)
  int xcd = bid & 7, slot = bid >> 3;
  int b = xcd + 8 * (slot >> 8);
  int tile = slot & 255;
  int it = tile >> 4, jt = tile & 15;

  int tid = threadIdx.x, w = tid >> 6, l = tid & 63;
  int lr = l >> 2, lc = (l & 3) * 8;  // staging: row-in-16, col(elem)
  int lm = l & 15, quad = l >> 4;
  int wr = (w >> 1) * 64, wc = (w & 1) * 64;

  const size_t qbase = ((size_t)b * TD + (size_t)it * 128) * DQ;
  const size_t kbase = ((size_t)b * TE + (size_t)jt * 128) * DQ;

  f32x4 acc[4][4];
  f32x4 zero = {0.f, 0.f, 0.f, 0.f};
  for (int mi = 0; mi < 4; ++mi)
    for (int ni = 0; ni < 4; ++ni) acc[mi][ni] = zero;

  for (int k0 = 0; k0 < DQ; k0 += 32) {
    for (int t = 0; t < 2; ++t) {
      int rg = (w * 2 + t) * 16;
      gload_lds16(Qb + qbase + (size_t)(rg + lr) * DQ + k0 + lc, &As[rg * 32]);
      gload_lds16(Kb + kbase + (size_t)(rg + lr) * DQ + k0 + lc, &Bs[rg * 32]);
    }
    __syncthreads();
    bf16x8 af[4], bfr[4];
    for (int mi = 0; mi < 4; ++mi)
      af[mi] = *(const bf16x8*)&As[(wr + mi * 16 + lm) * 32 + quad * 8];
    for (int ni = 0; ni < 4; ++ni)
      bfr[ni] = *(const bf16x8*)&Bs[(wc + ni * 16 + lm) * 32 + quad * 8];
    for (int mi = 0; mi < 4; ++mi)
      for (int ni = 0; ni < 4; ++ni)
        acc[mi][ni] = __builtin_amdgcn_mfma_f32_16x16x32_bf16(af[mi], bfr[ni],
                                                              acc[mi][ni], 0, 0, 0);
    __syncthreads();
  }

  // epilogue: C/D layout col=lane&15, row=quad*4+reg (m89-verified)
  // + per-row partial softmax stats over this block's 128 columns
  for (int mi = 0; mi < 4; ++mi) {
    int ib = it * 128 + wr + mi * 16 + quad * 4;
    float lg[4][4];  // [ni][r] — fully unrolled, static indices only
#pragma unroll
    for (int ni = 0; ni < 4; ++ni) {
      int j = jt * 128 + wc + ni * 16 + lm;
      float* op = Sc + ((size_t)b * TD + ib) * TE + j;
#pragma unroll
      for (int r = 0; r < 4; ++r) {
        float v = acc[mi][ni][r] * SCALE - (float)(ib + r - j) * WBIAS;
        lg[ni][r] = v;
        op[(size_t)r * TE] = v;
      }
    }
    float rmax[4], rsum[4];
#pragma unroll
    for (int r = 0; r < 4; ++r) {
      float m = fmaxf(fmaxf(lg[0][r], lg[1][r]), fmaxf(lg[2][r], lg[3][r]));
#pragma unroll
      for (int off = 8; off; off >>= 1) m = fmaxf(m, __shfl_xor(m, off));
      rmax[r] = m;
    }
#pragma unroll
    for (int r = 0; r < 4; ++r) {
      float s = __expf(lg[0][r] - rmax[r]) + __expf(lg[1][r] - rmax[r]) +
                __expf(lg[2][r] - rmax[r]) + __expf(lg[3][r] - rmax[r]);
#pragma unroll
      for (int off = 8; off; off >>= 1) s += __shfl_xor(s, off);
      rsum[r] = s;
    }
    if (lm == 0) {
      int p = jt * 2 + (w & 1);
#pragma unroll
      for (int r = 0; r < 4; ++r) {
        float* st = St + ((size_t)b * TD + ib + r) * DV;
        st[p] = rmax[r];
        st[32 + p] = rsum[r];
      }
    }
  }
}

// ---------------- GEMM2: P = exp(l-M)*invS (written to Sc); O = P @ V ----------------
// block: 64 i-rows x 512 v-cols, BK=32 over j; 4 waves, each 64x128 (4x8 16x16 tiles)
// Prologue merges the 32 per-row partials from St (=O region, overwritten by
// this block's own epilogue afterwards — single writer/reader per row).
__global__ __launch_bounds__(256) void k_gemm2(float* Sc,
                                               const unsigned short* __restrict__ Vt,
                                               float* O) {
  __shared__ __align__(16) unsigned short As[64 * 32];
  __shared__ __align__(16) unsigned short Bs[512 * 32];
  int bid = blockIdx.x;
  int xcd = bid & 7, slot = bid >> 3;
  int b = xcd + 8 * (slot >> 5);
  int it = slot & 31;
  int i0 = it * 64;

  int tid = threadIdx.x, w = tid >> 6, l = tid & 63;
  int lm = l & 15, quad = l >> 4;
  int lr = l >> 2, lc = (l & 3) * 8;
  int arow = tid >> 2, acg = (tid & 3) * 8;
  float* scp = Sc + ((size_t)b * TD + i0 + arow) * TE + acg;

  // merge row stats (4 threads per row do redundant work; reads are L2-hot)
  const float* st = O + ((size_t)b * TD + i0 + arow) * DV;
  float M = -3.0e38f;
#pragma unroll
  for (int p = 0; p < 32; ++p) M = fmaxf(M, st[p]);
  float S = 0.f;
#pragma unroll
  for (int p = 0; p < 32; ++p) S += st[32 + p] * __expf(st[p] - M);
  float invS = 1.0f / S;

  f32x4 acc[4][8];
  f32x4 zero = {0.f, 0.f, 0.f, 0.f};
  for (int mi = 0; mi < 4; ++mi)
    for (int ni = 0; ni < 8; ++ni) acc[mi][ni] = zero;

  for (int k0 = 0; k0 < TE; k0 += 32) {
    // A stage (VALU): read logits, normalize, write P to Sc, cast to bf16
    float4 f0 = *(const float4*)(scp + k0);
    float4 f1 = *(const float4*)(scp + k0 + 4);
    f0.x = __expf(f0.x - M) * invS;
    f0.y = __expf(f0.y - M) * invS;
    f0.z = __expf(f0.z - M) * invS;
    f0.w = __expf(f0.w - M) * invS;
    f1.x = __expf(f1.x - M) * invS;
    f1.y = __expf(f1.y - M) * invS;
    f1.z = __expf(f1.z - M) * invS;
    f1.w = __expf(f1.w - M) * invS;
    *(float4*)(scp + k0) = f0;       // scores output
    *(float4*)(scp + k0 + 4) = f1;
    *(ushort4*)&As[arow * 32 + acg] =
        make_ushort4(f2bf(f0.x), f2bf(f0.y), f2bf(f0.z), f2bf(f0.w));
    *(ushort4*)&As[arow * 32 + acg + 4] =
        make_ushort4(f2bf(f1.x), f2bf(f1.y), f2bf(f1.z), f2bf(f1.w));
    // B stage (async direct-to-LDS): Vt tile [512 v][32 j]
    for (int q = 0; q < 8; ++q) {
      int vr = (w * 8 + q) * 16;
      gload_lds16(Vt + ((size_t)b * DV + vr + lr) * TE + k0 + lc, &Bs[vr * 32]);
    }
    __syncthreads();
    bf16x8 af[4];
    for (int mi = 0; mi < 4; ++mi)
      af[mi] = *(const bf16x8*)&As[(mi * 16 + lm) * 32 + quad * 8];
    for (int ni = 0; ni < 8; ++ni) {
      bf16x8 bfr = *(const bf16x8*)&Bs[(w * 128 + ni * 16 + lm) * 32 + quad * 8];
      for (int mi = 0; mi < 4; ++mi)
        acc[mi][ni] = __builtin_amdgcn_mfma_f32_16x16x32_bf16(af[mi], bfr,
                                                              acc[mi][ni], 0, 0, 0);
    }
    __syncthreads();
  }

  for (int mi = 0; mi < 4; ++mi) {
    int ib = i0 + mi * 16 + quad * 4;
    for (int ni = 0; ni < 8; ++ni) {
      int vc = w * 128 + ni * 16 + lm;
      float* op = O + ((size_t)b * TD + ib) * DV + vc;
      for (int r = 0; r < 4; ++r) op[(size_t)r * DV] = acc[mi][ni][r];
    }
  }
}

extern "C" void kernel_launch(void* const* d_in, const int* in_sizes, int n_in,
                              void* d_out, int out_size, void* d_ws, size_t ws_size,
                              hipStream_t stream) {
  const float* Q = (const float*)d_in[0];
  const float* K = (const float*)d_in[1];
  const float* V = (const float*)d_in[2];
  float* out = (float*)d_out;
  float* O = out;                                  // summaries [32,2048,512]
  float* Sc = out + (size_t)NB * TD * DV;          // scores    [32,2048,2048]

  unsigned short* qb = (unsigned short*)d_ws;                // 67.1 MB
  unsigned short* kb = qb + (size_t)NB * TD * DQ;            // 67.1 MB
  unsigned short* vt = kb + (size_t)NB * TE * DQ;            // 67.1 MB

  k_cvt2<<<65536, 256, 0, stream>>>((const float4*)Q, (ushort4*)qb,
                                    (const float4*)K, (ushort4*)kb);
  k_vtrans<<<dim3(16, 64, 32), 256, 0, stream>>>(V, vt);
  k_gemm1<<<8192, 256, 0, stream>>>(qb, kb, Sc, O);
  k_gemm2<<<1024, 256, 0, stream>>>(Sc, vt, O);
}